// Round 2
// baseline (2424.787 us; speedup 1.0000x reference)
//
#include <hip/hip_runtime.h>
#include <hip/hip_bf16.h>

// Problem dims (fixed): B=4, L=512, T=2048 tokens, IN=128, DM=512, DI=1024,
// DS=16, DC=4, DTR=32, NL=2, E=8, NC=10.  All inputs/outputs are fp32.

#define T_TOK 2048

// ---------------- generic tiled matmul: C = act(A @ W^T + bias) (+ add) -----
// A: [M,lda] fp32, W: [N,ldw] fp32 row-major (row n = output feature n)
// ACT: 0 none, 1 gelu(exact), 2 relu, 3 softplus
template <int BM, int BN, int ACT, bool HB, bool HA>
__global__ __launch_bounds__(256) void mm_kernel(const float* __restrict__ A, int lda,
                                                 const float* __restrict__ W, int ldw,
                                                 const float* __restrict__ bias,
                                                 const float* __restrict__ addsrc,
                                                 float* __restrict__ C, int ldc, int K) {
  constexpr int TM = BM / 16;
  constexpr int TN = BN / 16;
  __shared__ float As[16][BM + 4];
  __shared__ float Ws[16][BN + 4];
  const int tid = threadIdx.x;
  const int tx = tid & 15, ty = tid >> 4;
  const int m0 = blockIdx.y * BM, n0 = blockIdx.x * BN;

  float acc[TM][TN];
#pragma unroll
  for (int i = 0; i < TM; ++i)
#pragma unroll
    for (int j = 0; j < TN; ++j) acc[i][j] = 0.f;

  for (int k0 = 0; k0 < K; k0 += 16) {
    for (int idx = tid; idx < BM * 16; idx += 256) {
      int r = idx >> 4, c = idx & 15;
      As[c][r] = A[(size_t)(m0 + r) * lda + k0 + c];
    }
    for (int idx = tid; idx < BN * 16; idx += 256) {
      int r = idx >> 4, c = idx & 15;
      Ws[c][r] = W[(size_t)(n0 + r) * ldw + k0 + c];
    }
    __syncthreads();
#pragma unroll
    for (int kk = 0; kk < 16; ++kk) {
      float a[TM], b[TN];
#pragma unroll
      for (int i = 0; i < TM; ++i) a[i] = As[kk][ty * TM + i];
#pragma unroll
      for (int j = 0; j < TN; ++j) b[j] = Ws[kk][tx * TN + j];
#pragma unroll
      for (int i = 0; i < TM; ++i)
#pragma unroll
        for (int j = 0; j < TN; ++j) acc[i][j] = fmaf(a[i], b[j], acc[i][j]);
    }
    __syncthreads();
  }

#pragma unroll
  for (int i = 0; i < TM; ++i) {
    int r = m0 + ty * TM + i;
#pragma unroll
    for (int j = 0; j < TN; ++j) {
      int n = n0 + tx * TN + j;
      float v = acc[i][j];
      if (HB) v += bias[n];
      if (ACT == 1) v = 0.5f * v * (1.f + erff(v * 0.70710678118654752f));
      else if (ACT == 2) v = fmaxf(v, 0.f);
      else if (ACT == 3) v = (v > 0.f) ? (v + log1pf(expf(-v))) : log1pf(expf(v));
      if (HA) v += addsrc[(size_t)r * ldc + n];
      C[(size_t)r * ldc + n] = v;
    }
  }
}

// ---------------- LayerNorm (one wave per 512-wide token row) ---------------
__global__ __launch_bounds__(256) void ln_kernel(const float* __restrict__ in,
                                                 const float* __restrict__ g,
                                                 const float* __restrict__ b,
                                                 float* __restrict__ out) {
  int wave = threadIdx.x >> 6, lane = threadIdx.x & 63;
  int t = blockIdx.x * 4 + wave;
  const float* row = in + (size_t)t * 512;
  float v[8];
  float s = 0.f;
#pragma unroll
  for (int j = 0; j < 8; ++j) { v[j] = row[lane + j * 64]; s += v[j]; }
#pragma unroll
  for (int o = 1; o < 64; o <<= 1) s += __shfl_xor(s, o);
  float mu = s * (1.f / 512.f);
  float q = 0.f;
#pragma unroll
  for (int j = 0; j < 8; ++j) { float d = v[j] - mu; q += d * d; }
#pragma unroll
  for (int o = 1; o < 64; o <<= 1) q += __shfl_xor(q, o);
  float rstd = rsqrtf(q * (1.f / 512.f) + 1e-5f);
  float* orow = out + (size_t)t * 512;
#pragma unroll
  for (int j = 0; j < 8; ++j) {
    int c = lane + j * 64;
    orow[c] = (v[j] - mu) * rstd * g[c] + b[c];
  }
}

// ------------- depthwise causal conv (dir 0) / anti-causal (dir 1) + silu ---
__global__ __launch_bounds__(256) void conv_silu_kernel(const float* __restrict__ xz,
                                                        const float* __restrict__ cw,
                                                        const float* __restrict__ cb,
                                                        float* __restrict__ xi2) {
  int dir = blockIdx.z;
  int idx = blockIdx.x * 256 + threadIdx.x;  // over T*1024
  int d = idx & 1023, t = idx >> 10;
  int b = t >> 9, tl = t & 511;
  float acc = cb[d];
#pragma unroll
  for (int k = 0; k < 4; ++k) {
    int src = (dir == 0) ? (tl - 3 + k) : (tl + 3 - k);
    if (src >= 0 && src < 512)
      acc += cw[d * 4 + k] * xz[(size_t)(b * 512 + src) * 2048 + d];
  }
  xi2[(size_t)dir * T_TOK * 1024 + idx] = acc / (1.f + expf(-acc));
}

// ---------------- selective scan, both directions concurrently --------------
__global__ __launch_bounds__(256) void scan_kernel(const float* __restrict__ xdbl2,
                                                   const float* __restrict__ dt2,
                                                   const float* __restrict__ xi2,
                                                   const float* __restrict__ alog,
                                                   const float* __restrict__ Dp,
                                                   float* __restrict__ y2) {
  const int dir = blockIdx.z;
  const int b = blockIdx.y;
  const int s = threadIdx.x & 15;
  const int dl = threadIdx.x >> 4;
  const int d = blockIdx.x * 16 + dl;
  const float A = -expf(alog[d * 16 + s]);
  const float Dv = Dp[d];
  const float* dt = dt2 + (size_t)dir * T_TOK * 1024;
  const float* xi = xi2 + (size_t)dir * T_TOK * 1024;
  const float* xd = xdbl2 + (size_t)dir * T_TOK * 64;
  float* y = y2 + (size_t)dir * T_TOK * 1024;
  float h = 0.f;
#pragma unroll 4
  for (int t = 0; t < 512; ++t) {
    int tt = dir ? (511 - t) : t;
    int row = b * 512 + tt;
    float dtv = dt[row * 1024 + d];
    float xiv = xi[row * 1024 + d];
    float Bv = xd[row * 64 + 32 + s];
    float Cv = xd[row * 64 + 48 + s];
    float dA = expf(dtv * A);
    h = fmaf(dA, h, dtv * Bv * xiv);
    float p = h * Cv;
    p += __shfl_xor(p, 1);
    p += __shfl_xor(p, 2);
    p += __shfl_xor(p, 4);
    p += __shfl_xor(p, 8);
    if (s == 0) y[row * 1024 + d] = p + Dv * xiv;
  }
}

// ---------------- g = silu(z) * (y_fwd + y_bwd) ------------------------------
__global__ __launch_bounds__(256) void gmul_kernel(const float* __restrict__ xz,
                                                   const float* __restrict__ y2,
                                                   float* __restrict__ g) {
  int idx = blockIdx.x * 256 + threadIdx.x;  // over T*1024
  int d = idx & 1023, t = idx >> 10;
  float z = xz[(size_t)t * 2048 + 1024 + d];
  float y = y2[idx] + y2[(size_t)T_TOK * 1024 + idx];
  g[idx] = z / (1.f + expf(-z)) * y;
}

// ---------------- MoE gate: topv = max(softmax(h@gw^T+gb)) ------------------
__global__ __launch_bounds__(256) void gate_kernel(const float* __restrict__ h,
                                                   const float* __restrict__ gw,
                                                   const float* __restrict__ gb,
                                                   float* __restrict__ topv) {
  int wave = threadIdx.x >> 6, lane = threadIdx.x & 63;
  int t = blockIdx.x * 4 + wave;
  float acc[8] = {0.f, 0.f, 0.f, 0.f, 0.f, 0.f, 0.f, 0.f};
  for (int k = lane; k < 512; k += 64) {
    float hv = h[(size_t)t * 512 + k];
#pragma unroll
    for (int e = 0; e < 8; ++e) acc[e] = fmaf(hv, gw[e * 512 + k], acc[e]);
  }
#pragma unroll
  for (int e = 0; e < 8; ++e)
#pragma unroll
    for (int o = 1; o < 64; o <<= 1) acc[e] += __shfl_xor(acc[e], o);
  if (lane == 0) {
    float zmax = -1e30f;
#pragma unroll
    for (int e = 0; e < 8; ++e) {
      acc[e] += gb[e];
      zmax = fmaxf(zmax, acc[e]);
    }
    float ssum = 0.f;
#pragma unroll
    for (int e = 0; e < 8; ++e) ssum += expf(acc[e] - zmax);
    topv[t] = 1.f / ssum;
  }
}

// ---------------- h = e3 * topv[t] ------------------------------------------
__global__ __launch_bounds__(256) void scale_kernel(const float* __restrict__ e3,
                                                    const float* __restrict__ topv,
                                                    float* __restrict__ h) {
  int idx = blockIdx.x * 256 + threadIdx.x;  // over T*512
  h[idx] = e3[idx] * topv[idx >> 9];
}

// ---------------- final head: out = h @ fcw^T + fcb (f32 out) ---------------
__global__ __launch_bounds__(256) void final_kernel(const float* __restrict__ h,
                                                    const float* __restrict__ fcw,
                                                    const float* __restrict__ fcb,
                                                    float* __restrict__ out) {
  int wave = threadIdx.x >> 6, lane = threadIdx.x & 63;
  int t = blockIdx.x * 4 + wave;
  float acc[10] = {0.f, 0.f, 0.f, 0.f, 0.f, 0.f, 0.f, 0.f, 0.f, 0.f};
  for (int k = lane; k < 512; k += 64) {
    float hv = h[(size_t)t * 512 + k];
#pragma unroll
    for (int c = 0; c < 10; ++c) acc[c] = fmaf(hv, fcw[c * 512 + k], acc[c]);
  }
#pragma unroll
  for (int c = 0; c < 10; ++c)
#pragma unroll
    for (int o = 1; o < 64; o <<= 1) acc[c] += __shfl_xor(acc[c], o);
  if (lane == 0) {
#pragma unroll
    for (int c = 0; c < 10; ++c)
      out[(size_t)t * 10 + c] = acc[c] + fcb[c];
  }
}

extern "C" void kernel_launch(void* const* d_in, const int* in_sizes, int n_in,
                              void* d_out, int out_size, void* d_ws, size_t ws_size,
                              hipStream_t stream) {
  (void)in_sizes; (void)n_in; (void)out_size; (void)ws_size;
  const float* x_in  = (const float*)d_in[0];
  const float* inp_w = (const float*)d_in[1];
  const float* inp_b = (const float*)d_in[2];
  const float* n1g   = (const float*)d_in[3];
  const float* n1b   = (const float*)d_in[4];
  const float* inw   = (const float*)d_in[5];
  const float* cw    = (const float*)d_in[6];
  const float* cb    = (const float*)d_in[7];
  const float* xpw   = (const float*)d_in[8];
  const float* dtw   = (const float*)d_in[9];
  const float* dtb   = (const float*)d_in[10];
  const float* alog  = (const float*)d_in[11];
  const float* Dp    = (const float*)d_in[12];
  const float* ow    = (const float*)d_in[13];
  const float* n2g   = (const float*)d_in[14];
  const float* n2b   = (const float*)d_in[15];
  const float* fw1   = (const float*)d_in[16];
  const float* fb1   = (const float*)d_in[17];
  const float* fw2   = (const float*)d_in[18];
  const float* fb2   = (const float*)d_in[19];
  const float* gw    = (const float*)d_in[20];
  const float* gb    = (const float*)d_in[21];
  const float* ew1   = (const float*)d_in[22];
  const float* eb1   = (const float*)d_in[23];
  const float* ew2   = (const float*)d_in[24];
  const float* eb2   = (const float*)d_in[25];
  const float* ew3   = (const float*)d_in[26];
  const float* eb3   = (const float*)d_in[27];
  const float* fcw   = (const float*)d_in[28];
  const float* fcb   = (const float*)d_in[29];

  float* p = (float*)d_ws;
  size_t off = 0;
  auto alloc = [&](size_t n) { float* r = p + off; off += n; return r; };
  float* h     = alloc(1048576);      // [T,512]
  float* res   = alloc(1048576);
  float* hn    = alloc(1048576);
  float* xz    = alloc(4194304);      // [T,2048]; also reused as ff1
  float* xi2   = alloc(2u * 2097152); // [2][T,1024]
  float* xdbl2 = alloc(2u * 131072);  // [2][T,64]
  float* dt2   = alloc(2u * 2097152); // [2][T,1024]
  float* y2    = alloc(2u * 2097152); // [2][T,1024]
  float* g     = alloc(2097152);      // [T,1024]
  float* fb    = alloc(1048576);      // [T,512]
  float* mbuf  = alloc(1048576);      // [T,512]
  float* e1    = alloc(524288);       // [T,256]
  float* e2    = alloc(524288);       // [T,256]
  float* e3    = alloc(1048576);      // [T,512]
  float* topv  = alloc(2048);         // [T]

  // h = x @ inp_w^T + inp_b
  mm_kernel<64, 64, 0, true, false><<<dim3(8, 32), 256, 0, stream>>>(
      x_in, 128, inp_w, 128, inp_b, nullptr, h, 512, 128);

  for (int i = 0; i < 2; ++i) {
    const float* inw_i  = inw + (size_t)i * 2048 * 512;
    const float* cw_i   = cw + (size_t)i * 1024 * 4;
    const float* cb_i   = cb + (size_t)i * 1024;
    const float* xpw_i  = xpw + (size_t)i * 64 * 1024;
    const float* dtw_i  = dtw + (size_t)i * 1024 * 32;
    const float* dtb_i  = dtb + (size_t)i * 1024;
    const float* alog_i = alog + (size_t)i * 1024 * 16;
    const float* Dp_i   = Dp + (size_t)i * 1024;
    const float* ow_i   = ow + (size_t)i * 512 * 1024;
    const float* fw1_i  = fw1 + (size_t)i * 2048 * 512;
    const float* fb1_i  = fb1 + (size_t)i * 2048;
    const float* fw2_i  = fw2 + (size_t)i * 512 * 2048;
    const float* fb2_i  = fb2 + (size_t)i * 512;

    hipMemcpyAsync(res, h, (size_t)1048576 * 4, hipMemcpyDeviceToDevice, stream);
    ln_kernel<<<512, 256, 0, stream>>>(h, n1g + i * 512, n1b + i * 512, hn);
    // xz = hn @ inw^T  [T,2048] (xi raw = cols 0..1023, z = cols 1024..2047)
    mm_kernel<64, 64, 0, false, false><<<dim3(32, 32), 256, 0, stream>>>(
        hn, 512, inw_i, 512, nullptr, nullptr, xz, 2048, 512);
    // conv(+silu), both directions
    conv_silu_kernel<<<dim3(8192, 1, 2), 256, 0, stream>>>(xz, cw_i, cb_i, xi2);
    for (int dir = 0; dir < 2; ++dir) {
      // xdbl = xi @ xpw^T  [T,64]
      mm_kernel<16, 64, 0, false, false><<<dim3(1, 128), 256, 0, stream>>>(
          xi2 + (size_t)dir * 2097152, 1024, xpw_i, 1024, nullptr, nullptr,
          xdbl2 + (size_t)dir * 131072, 64, 1024);
      // dt = softplus(xdbl[:, :32] @ dtw^T + dtb)  [T,1024]
      mm_kernel<64, 64, 3, true, false><<<dim3(16, 32), 256, 0, stream>>>(
          xdbl2 + (size_t)dir * 131072, 64, dtw_i, 32, dtb_i, nullptr,
          dt2 + (size_t)dir * 2097152, 1024, 32);
    }
    scan_kernel<<<dim3(64, 4, 2), 256, 0, stream>>>(xdbl2, dt2, xi2, alog_i, Dp_i, y2);
    gmul_kernel<<<8192, 256, 0, stream>>>(xz, y2, g);
    // f + bwd = g @ ow^T  [T,512]
    mm_kernel<64, 64, 0, false, false><<<dim3(8, 32), 256, 0, stream>>>(
        g, 1024, ow_i, 1024, nullptr, nullptr, fb, 512, 1024);
    ln_kernel<<<512, 256, 0, stream>>>(fb, n2g + i * 512, n2b + i * 512, mbuf);
    // ff1 = gelu(m @ fw1^T + fb1)  [T,2048]  (stored in xz)
    mm_kernel<64, 64, 1, true, false><<<dim3(32, 32), 256, 0, stream>>>(
        mbuf, 512, fw1_i, 512, fb1_i, nullptr, xz, 2048, 512);
    // h = ff1 @ fw2^T + fb2 + res  [T,512]
    mm_kernel<64, 64, 0, true, true><<<dim3(8, 32), 256, 0, stream>>>(
        xz, 2048, fw2_i, 2048, fb2_i, res, h, 512, 2048);
    // MoE
    gate_kernel<<<512, 256, 0, stream>>>(h, gw, gb, topv);
    mm_kernel<64, 64, 2, true, false><<<dim3(4, 32), 256, 0, stream>>>(
        h, 512, ew1, 512, eb1, nullptr, e1, 256, 512);
    mm_kernel<64, 64, 2, true, false><<<dim3(4, 32), 256, 0, stream>>>(
        e1, 256, ew2, 256, eb2, nullptr, e2, 256, 256);
    mm_kernel<64, 64, 2, true, false><<<dim3(8, 32), 256, 0, stream>>>(
        e2, 256, ew3, 256, eb3, nullptr, e3, 512, 256);
    scale_kernel<<<4096, 256, 0, stream>>>(e3, topv, h);
  }
  final_kernel<<<512, 256, 0, stream>>>(h, fcw, fcb, (float*)d_out);
}

// Round 3
// 1167.872 us; speedup vs baseline: 2.0762x; 2.0762x over previous
//
#include <hip/hip_runtime.h>
#include <hip/hip_bf16.h>

// Dims: B=4, L=512, T=2048 tokens, IN=128, DM=512, DI=1024, DS=16, DC=4,
// DTR=32, NL=2, E=8, NC=10. All inputs/outputs fp32.
// GEMMs run on MFMA bf16 with hi/lo split (3-term) for ~fp32 accuracy.

#define T_TOK 2048

typedef __bf16 bf16x8 __attribute__((ext_vector_type(8)));
typedef float f32x4 __attribute__((ext_vector_type(4)));
typedef unsigned int u32x4 __attribute__((ext_vector_type(4)));

static __device__ __forceinline__ unsigned short f2bf(float f) {
  unsigned int u = __builtin_bit_cast(unsigned int, f);
  unsigned int r = (u + 0x7fffu + ((u >> 16) & 1u)) >> 16;
  return (unsigned short)r;
}
static __device__ __forceinline__ float bf2f(unsigned short s) {
  unsigned int u = ((unsigned int)s) << 16;
  return __builtin_bit_cast(float, u);
}

// ---------------- weight pre-split: fp32 -> bf16 hi/lo planes ----------------
__global__ __launch_bounds__(256) void split_kernel(const float* __restrict__ in,
                                                    unsigned short* __restrict__ hi,
                                                    unsigned short* __restrict__ lo, int n) {
  int i4 = (blockIdx.x * 256 + threadIdx.x) * 4;
  if (i4 >= n) return;
#pragma unroll
  for (int j = 0; j < 4; ++j) {
    float v = in[i4 + j];
    unsigned short h = f2bf(v);
    hi[i4 + j] = h;
    lo[i4 + j] = f2bf(v - bf2f(h));
  }
}

// ---------------- MFMA GEMM: C = act(A @ W^T + bias) (+ add) ----------------
// A: [M,lda] fp32 (split on the fly). W: preconverted hi/lo bf16 planes [N,ldw].
// Tile 64x64, K-step 64. 4 waves (2x2), each wave 32x32 via 2x2 16x16 frags.
// ACT: 0 none, 1 gelu, 2 relu, 3 softplus.
template <int ACT, bool HB, bool HA>
__global__ __launch_bounds__(256) void mfmm_kernel(
    const float* __restrict__ A, int lda,
    const unsigned short* __restrict__ Wh, const unsigned short* __restrict__ Wl, int ldw,
    const float* __restrict__ bias, const float* __restrict__ addsrc,
    float* __restrict__ C, int ldc, int K) {
  __shared__ unsigned int lds[4 * 2048];  // Ah, Al, Bh, Bl: 64 rows x 32 uints (64 bf16)
  unsigned int* Ah = lds;
  unsigned int* Al = lds + 2048;
  unsigned int* Bh = lds + 4096;
  unsigned int* Bl = lds + 6144;

  const int tid = threadIdx.x;
  const int m0 = blockIdx.y * 64, n0 = blockIdx.x * 64;
  const int wid = tid >> 6, lane = tid & 63;
  const int wm = wid >> 1, wn = wid & 1;
  const int lr = lane & 15, kg = lane >> 4;

  // staging assignment: one row per lane-of-block, 16 k per thread
  const int sr = tid & 63;
  const int scg = tid >> 6;     // 0..3
  const int sc = scg * 16;      // k offset within tile
  const int s0 = (scg * 2) ^ (sr & 7);
  const int s1 = (scg * 2 + 1) ^ (sr & 7);

  f32x4 acc00 = {0.f, 0.f, 0.f, 0.f}, acc01 = acc00, acc10 = acc00, acc11 = acc00;

  for (int k0 = 0; k0 < K; k0 += 64) {
    const bool inK = (k0 + sc) < K;
    // ---- stage A (fp32 -> hi/lo bf16) ----
    unsigned int ah[8], al[8];
    if (inK) {
      const float* Ar = A + (size_t)(m0 + sr) * lda + k0 + sc;
#pragma unroll
      for (int j = 0; j < 8; ++j) {
        float v0 = Ar[2 * j], v1 = Ar[2 * j + 1];
        unsigned short h0 = f2bf(v0), h1 = f2bf(v1);
        unsigned short l0 = f2bf(v0 - bf2f(h0)), l1 = f2bf(v1 - bf2f(h1));
        ah[j] = (unsigned int)h0 | ((unsigned int)h1 << 16);
        al[j] = (unsigned int)l0 | ((unsigned int)l1 << 16);
      }
    } else {
#pragma unroll
      for (int j = 0; j < 8; ++j) { ah[j] = 0u; al[j] = 0u; }
    }
    // ---- stage W (copy preconverted planes) ----
    u32x4 wh0 = {0u, 0u, 0u, 0u}, wh1 = wh0, wl0 = wh0, wl1 = wh0;
    if (inK) {
      const unsigned short* Wr = Wh + (size_t)(n0 + sr) * ldw + k0 + sc;
      const unsigned short* Wr2 = Wl + (size_t)(n0 + sr) * ldw + k0 + sc;
      wh0 = *(const u32x4*)(Wr);
      wh1 = *(const u32x4*)(Wr + 8);
      wl0 = *(const u32x4*)(Wr2);
      wl1 = *(const u32x4*)(Wr2 + 8);
    }
    *(u32x4*)(Ah + sr * 32 + s0 * 4) = u32x4{ah[0], ah[1], ah[2], ah[3]};
    *(u32x4*)(Ah + sr * 32 + s1 * 4) = u32x4{ah[4], ah[5], ah[6], ah[7]};
    *(u32x4*)(Al + sr * 32 + s0 * 4) = u32x4{al[0], al[1], al[2], al[3]};
    *(u32x4*)(Al + sr * 32 + s1 * 4) = u32x4{al[4], al[5], al[6], al[7]};
    *(u32x4*)(Bh + sr * 32 + s0 * 4) = wh0;
    *(u32x4*)(Bh + sr * 32 + s1 * 4) = wh1;
    *(u32x4*)(Bl + sr * 32 + s0 * 4) = wl0;
    *(u32x4*)(Bl + sr * 32 + s1 * 4) = wl1;
    __syncthreads();

    // ---- compute ----
    const int ar0 = wm * 32 + lr, ar1 = wm * 32 + 16 + lr;
    const int br0 = wn * 32 + lr, br1 = wn * 32 + 16 + lr;
#pragma unroll
    for (int kh = 0; kh < 2; ++kh) {
      const int ksb = kh * 4 + kg;
      auto rd = [&](const unsigned int* P, int row) {
        return *(const bf16x8*)(P + row * 32 + ((ksb ^ (row & 7)) << 2));
      };
      bf16x8 a0h = rd(Ah, ar0), a0l = rd(Al, ar0);
      bf16x8 a1h = rd(Ah, ar1), a1l = rd(Al, ar1);
      bf16x8 b0h = rd(Bh, br0), b0l = rd(Bl, br0);
      bf16x8 b1h = rd(Bh, br1), b1l = rd(Bl, br1);
      acc00 = __builtin_amdgcn_mfma_f32_16x16x32_bf16(a0h, b0h, acc00, 0, 0, 0);
      acc00 = __builtin_amdgcn_mfma_f32_16x16x32_bf16(a0h, b0l, acc00, 0, 0, 0);
      acc00 = __builtin_amdgcn_mfma_f32_16x16x32_bf16(a0l, b0h, acc00, 0, 0, 0);
      acc01 = __builtin_amdgcn_mfma_f32_16x16x32_bf16(a0h, b1h, acc01, 0, 0, 0);
      acc01 = __builtin_amdgcn_mfma_f32_16x16x32_bf16(a0h, b1l, acc01, 0, 0, 0);
      acc01 = __builtin_amdgcn_mfma_f32_16x16x32_bf16(a0l, b1h, acc01, 0, 0, 0);
      acc10 = __builtin_amdgcn_mfma_f32_16x16x32_bf16(a1h, b0h, acc10, 0, 0, 0);
      acc10 = __builtin_amdgcn_mfma_f32_16x16x32_bf16(a1h, b0l, acc10, 0, 0, 0);
      acc10 = __builtin_amdgcn_mfma_f32_16x16x32_bf16(a1l, b0h, acc10, 0, 0, 0);
      acc11 = __builtin_amdgcn_mfma_f32_16x16x32_bf16(a1h, b1h, acc11, 0, 0, 0);
      acc11 = __builtin_amdgcn_mfma_f32_16x16x32_bf16(a1h, b1l, acc11, 0, 0, 0);
      acc11 = __builtin_amdgcn_mfma_f32_16x16x32_bf16(a1l, b1h, acc11, 0, 0, 0);
    }
    __syncthreads();
  }

  // ---- epilogue ----
  const float bv0 = HB ? bias[n0 + wn * 32 + lr] : 0.f;
  const float bv1 = HB ? bias[n0 + wn * 32 + 16 + lr] : 0.f;
  auto emit = [&](f32x4 d, int rbase, int c, float bv) {
#pragma unroll
    for (int reg = 0; reg < 4; ++reg) {
      int r = rbase + kg * 4 + reg;
      float v = d[reg];
      if (HB) v += bv;
      if (ACT == 1) v = 0.5f * v * (1.f + erff(v * 0.70710678118654752f));
      else if (ACT == 2) v = fmaxf(v, 0.f);
      else if (ACT == 3) v = (v > 0.f) ? (v + log1pf(expf(-v))) : log1pf(expf(v));
      if (HA) v += addsrc[(size_t)r * ldc + c];
      C[(size_t)r * ldc + c] = v;
    }
  };
  emit(acc00, m0 + wm * 32,      n0 + wn * 32 + lr,      bv0);
  emit(acc01, m0 + wm * 32,      n0 + wn * 32 + 16 + lr, bv1);
  emit(acc10, m0 + wm * 32 + 16, n0 + wn * 32 + lr,      bv0);
  emit(acc11, m0 + wm * 32 + 16, n0 + wn * 32 + 16 + lr, bv1);
}

// ---------------- LayerNorm (one wave per 512-wide token row) ---------------
__global__ __launch_bounds__(256) void ln_kernel(const float* __restrict__ in,
                                                 const float* __restrict__ g,
                                                 const float* __restrict__ b,
                                                 float* __restrict__ out) {
  int wave = threadIdx.x >> 6, lane = threadIdx.x & 63;
  int t = blockIdx.x * 4 + wave;
  const float* row = in + (size_t)t * 512;
  float v[8];
  float s = 0.f;
#pragma unroll
  for (int j = 0; j < 8; ++j) { v[j] = row[lane + j * 64]; s += v[j]; }
#pragma unroll
  for (int o = 1; o < 64; o <<= 1) s += __shfl_xor(s, o);
  float mu = s * (1.f / 512.f);
  float q = 0.f;
#pragma unroll
  for (int j = 0; j < 8; ++j) { float d = v[j] - mu; q += d * d; }
#pragma unroll
  for (int o = 1; o < 64; o <<= 1) q += __shfl_xor(q, o);
  float rstd = rsqrtf(q * (1.f / 512.f) + 1e-5f);
  float* orow = out + (size_t)t * 512;
#pragma unroll
  for (int j = 0; j < 8; ++j) {
    int c = lane + j * 64;
    orow[c] = (v[j] - mu) * rstd * g[c] + b[c];
  }
}

// ------------- depthwise causal conv (dir 0) / anti-causal (dir 1) + silu ---
__global__ __launch_bounds__(256) void conv_silu_kernel(const float* __restrict__ xz,
                                                        const float* __restrict__ cw,
                                                        const float* __restrict__ cb,
                                                        float* __restrict__ xi2) {
  int dir = blockIdx.z;
  int idx = blockIdx.x * 256 + threadIdx.x;  // over T*1024
  int d = idx & 1023, t = idx >> 10;
  int b = t >> 9, tl = t & 511;
  float acc = cb[d];
#pragma unroll
  for (int k = 0; k < 4; ++k) {
    int src = (dir == 0) ? (tl - 3 + k) : (tl + 3 - k);
    if (src >= 0 && src < 512)
      acc += cw[d * 4 + k] * xz[(size_t)(b * 512 + src) * 2048 + d];
  }
  xi2[(size_t)dir * T_TOK * 1024 + idx] = acc / (1.f + expf(-acc));
}

// ---------------- selective scan, both directions concurrently --------------
__global__ __launch_bounds__(256) void scan_kernel(const float* __restrict__ xdbl2,
                                                   const float* __restrict__ dt2,
                                                   const float* __restrict__ xi2,
                                                   const float* __restrict__ alog,
                                                   const float* __restrict__ Dp,
                                                   float* __restrict__ y2) {
  const int dir = blockIdx.z;
  const int b = blockIdx.y;
  const int s = threadIdx.x & 15;
  const int dl = threadIdx.x >> 4;
  const int d = blockIdx.x * 16 + dl;
  const float A = -expf(alog[d * 16 + s]);
  const float Dv = Dp[d];
  const float* dt = dt2 + (size_t)dir * T_TOK * 1024;
  const float* xi = xi2 + (size_t)dir * T_TOK * 1024;
  const float* xd = xdbl2 + (size_t)dir * T_TOK * 64;
  float* y = y2 + (size_t)dir * T_TOK * 1024;
  float h = 0.f;
#pragma unroll 4
  for (int t = 0; t < 512; ++t) {
    int tt = dir ? (511 - t) : t;
    int row = b * 512 + tt;
    float dtv = dt[row * 1024 + d];
    float xiv = xi[row * 1024 + d];
    float Bv = xd[row * 64 + 32 + s];
    float Cv = xd[row * 64 + 48 + s];
    float dA = expf(dtv * A);
    h = fmaf(dA, h, dtv * Bv * xiv);
    float p = h * Cv;
    p += __shfl_xor(p, 1);
    p += __shfl_xor(p, 2);
    p += __shfl_xor(p, 4);
    p += __shfl_xor(p, 8);
    if (s == 0) y[row * 1024 + d] = p + Dv * xiv;
  }
}

// ---------------- g = silu(z) * (y_fwd + y_bwd) ------------------------------
__global__ __launch_bounds__(256) void gmul_kernel(const float* __restrict__ xz,
                                                   const float* __restrict__ y2,
                                                   float* __restrict__ g) {
  int idx = blockIdx.x * 256 + threadIdx.x;  // over T*1024
  int d = idx & 1023, t = idx >> 10;
  float z = xz[(size_t)t * 2048 + 1024 + d];
  float y = y2[idx] + y2[(size_t)T_TOK * 1024 + idx];
  g[idx] = z / (1.f + expf(-z)) * y;
}

// ---------------- MoE gate: topv = max(softmax(h@gw^T+gb)) ------------------
__global__ __launch_bounds__(256) void gate_kernel(const float* __restrict__ h,
                                                   const float* __restrict__ gw,
                                                   const float* __restrict__ gb,
                                                   float* __restrict__ topv) {
  int wave = threadIdx.x >> 6, lane = threadIdx.x & 63;
  int t = blockIdx.x * 4 + wave;
  float acc[8] = {0.f, 0.f, 0.f, 0.f, 0.f, 0.f, 0.f, 0.f};
  for (int k = lane; k < 512; k += 64) {
    float hv = h[(size_t)t * 512 + k];
#pragma unroll
    for (int e = 0; e < 8; ++e) acc[e] = fmaf(hv, gw[e * 512 + k], acc[e]);
  }
#pragma unroll
  for (int e = 0; e < 8; ++e)
#pragma unroll
    for (int o = 1; o < 64; o <<= 1) acc[e] += __shfl_xor(acc[e], o);
  if (lane == 0) {
    float zmax = -1e30f;
#pragma unroll
    for (int e = 0; e < 8; ++e) {
      acc[e] += gb[e];
      zmax = fmaxf(zmax, acc[e]);
    }
    float ssum = 0.f;
#pragma unroll
    for (int e = 0; e < 8; ++e) ssum += expf(acc[e] - zmax);
    topv[t] = 1.f / ssum;
  }
}

// ---------------- h = e3 * topv[t] ------------------------------------------
__global__ __launch_bounds__(256) void scale_kernel(const float* __restrict__ e3,
                                                    const float* __restrict__ topv,
                                                    float* __restrict__ h) {
  int idx = blockIdx.x * 256 + threadIdx.x;  // over T*512
  h[idx] = e3[idx] * topv[idx >> 9];
}

// ---------------- final head: out = h @ fcw^T + fcb (f32 out) ---------------
__global__ __launch_bounds__(256) void final_kernel(const float* __restrict__ h,
                                                    const float* __restrict__ fcw,
                                                    const float* __restrict__ fcb,
                                                    float* __restrict__ out) {
  int wave = threadIdx.x >> 6, lane = threadIdx.x & 63;
  int t = blockIdx.x * 4 + wave;
  float acc[10] = {0.f, 0.f, 0.f, 0.f, 0.f, 0.f, 0.f, 0.f, 0.f, 0.f};
  for (int k = lane; k < 512; k += 64) {
    float hv = h[(size_t)t * 512 + k];
#pragma unroll
    for (int c = 0; c < 10; ++c) acc[c] = fmaf(hv, fcw[c * 512 + k], acc[c]);
  }
#pragma unroll
  for (int c = 0; c < 10; ++c)
#pragma unroll
    for (int o = 1; o < 64; o <<= 1) acc[c] += __shfl_xor(acc[c], o);
  if (lane == 0) {
#pragma unroll
    for (int c = 0; c < 10; ++c)
      out[(size_t)t * 10 + c] = acc[c] + fcb[c];
  }
}

extern "C" void kernel_launch(void* const* d_in, const int* in_sizes, int n_in,
                              void* d_out, int out_size, void* d_ws, size_t ws_size,
                              hipStream_t stream) {
  (void)in_sizes; (void)n_in; (void)out_size; (void)ws_size;
  const float* x_in  = (const float*)d_in[0];
  const float* inp_w = (const float*)d_in[1];
  const float* inp_b = (const float*)d_in[2];
  const float* n1g   = (const float*)d_in[3];
  const float* n1b   = (const float*)d_in[4];
  const float* inw   = (const float*)d_in[5];
  const float* cw    = (const float*)d_in[6];
  const float* cb    = (const float*)d_in[7];
  const float* xpw   = (const float*)d_in[8];
  const float* dtw   = (const float*)d_in[9];
  const float* dtb   = (const float*)d_in[10];
  const float* alog  = (const float*)d_in[11];
  const float* Dp    = (const float*)d_in[12];
  const float* ow    = (const float*)d_in[13];
  const float* n2g   = (const float*)d_in[14];
  const float* n2b   = (const float*)d_in[15];
  const float* fw1   = (const float*)d_in[16];
  const float* fb1   = (const float*)d_in[17];
  const float* fw2   = (const float*)d_in[18];
  const float* fb2   = (const float*)d_in[19];
  const float* gw    = (const float*)d_in[20];
  const float* gb    = (const float*)d_in[21];
  const float* ew1   = (const float*)d_in[22];
  const float* eb1   = (const float*)d_in[23];
  const float* ew2   = (const float*)d_in[24];
  const float* eb2   = (const float*)d_in[25];
  const float* ew3   = (const float*)d_in[26];
  const float* eb3   = (const float*)d_in[27];
  const float* fcw   = (const float*)d_in[28];
  const float* fcb   = (const float*)d_in[29];

  float* p = (float*)d_ws;
  size_t off = 0;
  auto alloc = [&](size_t n) { float* r = p + off; off += n; return r; };
  float* h     = alloc(1048576);      // [T,512]
  float* res   = alloc(1048576);
  float* hn    = alloc(1048576);
  float* xz    = alloc(4194304);      // [T,2048]; reused as ff1
  float* xi2   = alloc(2u * 2097152); // [2][T,1024]
  float* xdbl2 = alloc(2u * 131072);  // [2][T,64]
  float* dt2   = alloc(2u * 2097152); // [2][T,1024]
  float* y2    = alloc(2u * 2097152); // [2][T,1024]
  float* g     = alloc(2097152);      // [T,1024]
  float* fb    = alloc(1048576);      // [T,512]
  float* mbuf  = alloc(1048576);      // [T,512]
  float* e1    = alloc(524288);       // [T,256]
  float* e2    = alloc(524288);       // [T,256]
  float* e3    = alloc(1048576);      // [T,512]
  float* topv  = alloc(2048);         // [T]

  // bf16 hi/lo weight planes
  unsigned short* q = (unsigned short*)(p + off);
  size_t qoff = 0;
  auto ualloc = [&](size_t n) { unsigned short* r = q + qoff; qoff += n; return r; };
  unsigned short *inpwH = ualloc(65536),  *inpwL = ualloc(65536);
  unsigned short *inwH  = ualloc(2097152), *inwL  = ualloc(2097152);
  unsigned short *xpwH  = ualloc(131072),  *xpwL  = ualloc(131072);
  unsigned short *dtwH  = ualloc(65536),   *dtwL  = ualloc(65536);
  unsigned short *owH   = ualloc(1048576), *owL   = ualloc(1048576);
  unsigned short *fw1H  = ualloc(2097152), *fw1L  = ualloc(2097152);
  unsigned short *fw2H  = ualloc(2097152), *fw2L  = ualloc(2097152);
  unsigned short *ew1H  = ualloc(131072),  *ew1L  = ualloc(131072);
  unsigned short *ew2H  = ualloc(65536),   *ew2L  = ualloc(65536);
  unsigned short *ew3H  = ualloc(131072),  *ew3L  = ualloc(131072);

  auto split = [&](const float* src, unsigned short* hi, unsigned short* lo, int n) {
    split_kernel<<<(n / 4 + 255) / 256, 256, 0, stream>>>(src, hi, lo, n);
  };
  split(inp_w, inpwH, inpwL, 65536);
  split(inw,   inwH,  inwL,  2097152);
  split(xpw,   xpwH,  xpwL,  131072);
  split(dtw,   dtwH,  dtwL,  65536);
  split(ow,    owH,   owL,   1048576);
  split(fw1,   fw1H,  fw1L,  2097152);
  split(fw2,   fw2H,  fw2L,  2097152);
  split(ew1,   ew1H,  ew1L,  131072);
  split(ew2,   ew2H,  ew2L,  65536);
  split(ew3,   ew3H,  ew3L,  131072);

  // h = x @ inp_w^T + inp_b   [T,512], K=128
  mfmm_kernel<0, true, false><<<dim3(8, 32), 256, 0, stream>>>(
      x_in, 128, inpwH, inpwL, 128, inp_b, nullptr, h, 512, 128);

  for (int i = 0; i < 2; ++i) {
    const size_t wo = (size_t)i;
    hipMemcpyAsync(res, h, (size_t)1048576 * 4, hipMemcpyDeviceToDevice, stream);
    ln_kernel<<<512, 256, 0, stream>>>(h, n1g + i * 512, n1b + i * 512, hn);
    // xz = hn @ inw^T  [T,2048], K=512
    mfmm_kernel<0, false, false><<<dim3(32, 32), 256, 0, stream>>>(
        hn, 512, inwH + wo * 1048576, inwL + wo * 1048576, 512, nullptr, nullptr, xz, 2048, 512);
    // conv(+silu), both directions
    conv_silu_kernel<<<dim3(8192, 1, 2), 256, 0, stream>>>(xz, cw + i * 4096, cb + i * 1024, xi2);
    // xdbl (both dirs fused, M=4096) = xi @ xpw^T  [.,64], K=1024
    mfmm_kernel<0, false, false><<<dim3(1, 64), 256, 0, stream>>>(
        xi2, 1024, xpwH + wo * 65536, xpwL + wo * 65536, 1024, nullptr, nullptr, xdbl2, 64, 1024);
    // dt (both dirs fused, M=4096) = softplus(xdbl[:, :32] @ dtw^T + dtb)  [.,1024], K=32
    mfmm_kernel<3, true, false><<<dim3(16, 64), 256, 0, stream>>>(
        xdbl2, 64, dtwH + wo * 32768, dtwL + wo * 32768, 32, dtb + i * 1024, nullptr, dt2, 1024, 32);
    scan_kernel<<<dim3(64, 4, 2), 256, 0, stream>>>(xdbl2, dt2, xi2, alog + i * 16384, Dp + i * 1024, y2);
    gmul_kernel<<<8192, 256, 0, stream>>>(xz, y2, g);
    // f + bwd = g @ ow^T  [T,512], K=1024
    mfmm_kernel<0, false, false><<<dim3(8, 32), 256, 0, stream>>>(
        g, 1024, owH + wo * 524288, owL + wo * 524288, 1024, nullptr, nullptr, fb, 512, 1024);
    ln_kernel<<<512, 256, 0, stream>>>(fb, n2g + i * 512, n2b + i * 512, mbuf);
    // ff1 = gelu(m @ fw1^T + fb1)  [T,2048], K=512 (into xz)
    mfmm_kernel<1, true, false><<<dim3(32, 32), 256, 0, stream>>>(
        mbuf, 512, fw1H + wo * 1048576, fw1L + wo * 1048576, 512, fb1 + i * 2048, nullptr, xz, 2048, 512);
    // h = ff1 @ fw2^T + fb2 + res  [T,512], K=2048
    mfmm_kernel<0, true, true><<<dim3(8, 32), 256, 0, stream>>>(
        xz, 2048, fw2H + wo * 1048576, fw2L + wo * 1048576, 2048, fb2 + i * 512, res, h, 512, 2048);
    // MoE
    gate_kernel<<<512, 256, 0, stream>>>(h, gw, gb, topv);
    mfmm_kernel<2, true, false><<<dim3(4, 32), 256, 0, stream>>>(
        h, 512, ew1H, ew1L, 512, eb1, nullptr, e1, 256, 512);
    mfmm_kernel<2, true, false><<<dim3(4, 32), 256, 0, stream>>>(
        e1, 256, ew2H, ew2L, 256, eb2, nullptr, e2, 256, 256);
    mfmm_kernel<2, true, false><<<dim3(8, 32), 256, 0, stream>>>(
        e2, 256, ew3H, ew3L, 256, eb3, nullptr, e3, 512, 256);
    scale_kernel<<<4096, 256, 0, stream>>>(e3, topv, h);
  }
  final_kernel<<<512, 256, 0, stream>>>(h, fcw, fcb, (float*)d_out);
}

// Round 4
// 894.270 us; speedup vs baseline: 2.7115x; 1.3059x over previous
//
#include <hip/hip_runtime.h>
#include <hip/hip_bf16.h>

// Dims: B=4, L=512, T=2048 tokens, IN=128, DM=512, DI=1024, DS=16, DC=4,
// DTR=32, NL=2, E=8, NC=10. All inputs/outputs fp32.
// GEMMs: MFMA bf16 hi/lo split (3-term). Scan: 16-chunk parallel linear scan.

#define T_TOK 2048
#define NCH 16
#define CS 32

typedef __bf16 bf16x8 __attribute__((ext_vector_type(8)));
typedef float f32x4 __attribute__((ext_vector_type(4)));
typedef unsigned int u32x4 __attribute__((ext_vector_type(4)));

static __device__ __forceinline__ unsigned short f2bf(float f) {
  unsigned int u = __builtin_bit_cast(unsigned int, f);
  unsigned int r = (u + 0x7fffu + ((u >> 16) & 1u)) >> 16;
  return (unsigned short)r;
}
static __device__ __forceinline__ float bf2f(unsigned short s) {
  unsigned int u = ((unsigned int)s) << 16;
  return __builtin_bit_cast(float, u);
}

// ---------------- weight pre-split: fp32 -> bf16 hi/lo planes ----------------
__global__ __launch_bounds__(256) void split_kernel(const float* __restrict__ in,
                                                    unsigned short* __restrict__ hi,
                                                    unsigned short* __restrict__ lo, int n) {
  int i4 = (blockIdx.x * 256 + threadIdx.x) * 4;
  if (i4 >= n) return;
#pragma unroll
  for (int j = 0; j < 4; ++j) {
    float v = in[i4 + j];
    unsigned short h = f2bf(v);
    hi[i4 + j] = h;
    lo[i4 + j] = f2bf(v - bf2f(h));
  }
}

// ---------------- MFMA GEMM: C = act(A @ W^T + bias) (+ add) ----------------
template <int ACT, bool HB, bool HA>
__global__ __launch_bounds__(256) void mfmm_kernel(
    const float* __restrict__ A, int lda,
    const unsigned short* __restrict__ Wh, const unsigned short* __restrict__ Wl, int ldw,
    const float* __restrict__ bias, const float* __restrict__ addsrc,
    float* __restrict__ C, int ldc, int K) {
  __shared__ unsigned int lds[4 * 2048];
  unsigned int* Ah = lds;
  unsigned int* Al = lds + 2048;
  unsigned int* Bh = lds + 4096;
  unsigned int* Bl = lds + 6144;

  const int tid = threadIdx.x;
  const int m0 = blockIdx.y * 64, n0 = blockIdx.x * 64;
  const int wid = tid >> 6, lane = tid & 63;
  const int wm = wid >> 1, wn = wid & 1;
  const int lr = lane & 15, kg = lane >> 4;

  const int sr = tid & 63;
  const int scg = tid >> 6;
  const int sc = scg * 16;
  const int s0 = (scg * 2) ^ (sr & 7);
  const int s1 = (scg * 2 + 1) ^ (sr & 7);

  f32x4 acc00 = {0.f, 0.f, 0.f, 0.f}, acc01 = acc00, acc10 = acc00, acc11 = acc00;

  for (int k0 = 0; k0 < K; k0 += 64) {
    const bool inK = (k0 + sc) < K;
    unsigned int ah[8], al[8];
    if (inK) {
      const float* Ar = A + (size_t)(m0 + sr) * lda + k0 + sc;
#pragma unroll
      for (int j = 0; j < 8; ++j) {
        float v0 = Ar[2 * j], v1 = Ar[2 * j + 1];
        unsigned short h0 = f2bf(v0), h1 = f2bf(v1);
        unsigned short l0 = f2bf(v0 - bf2f(h0)), l1 = f2bf(v1 - bf2f(h1));
        ah[j] = (unsigned int)h0 | ((unsigned int)h1 << 16);
        al[j] = (unsigned int)l0 | ((unsigned int)l1 << 16);
      }
    } else {
#pragma unroll
      for (int j = 0; j < 8; ++j) { ah[j] = 0u; al[j] = 0u; }
    }
    u32x4 wh0 = {0u, 0u, 0u, 0u}, wh1 = wh0, wl0 = wh0, wl1 = wh0;
    if (inK) {
      const unsigned short* Wr = Wh + (size_t)(n0 + sr) * ldw + k0 + sc;
      const unsigned short* Wr2 = Wl + (size_t)(n0 + sr) * ldw + k0 + sc;
      wh0 = *(const u32x4*)(Wr);
      wh1 = *(const u32x4*)(Wr + 8);
      wl0 = *(const u32x4*)(Wr2);
      wl1 = *(const u32x4*)(Wr2 + 8);
    }
    *(u32x4*)(Ah + sr * 32 + s0 * 4) = u32x4{ah[0], ah[1], ah[2], ah[3]};
    *(u32x4*)(Ah + sr * 32 + s1 * 4) = u32x4{ah[4], ah[5], ah[6], ah[7]};
    *(u32x4*)(Al + sr * 32 + s0 * 4) = u32x4{al[0], al[1], al[2], al[3]};
    *(u32x4*)(Al + sr * 32 + s1 * 4) = u32x4{al[4], al[5], al[6], al[7]};
    *(u32x4*)(Bh + sr * 32 + s0 * 4) = wh0;
    *(u32x4*)(Bh + sr * 32 + s1 * 4) = wh1;
    *(u32x4*)(Bl + sr * 32 + s0 * 4) = wl0;
    *(u32x4*)(Bl + sr * 32 + s1 * 4) = wl1;
    __syncthreads();

    const int ar0 = wm * 32 + lr, ar1 = wm * 32 + 16 + lr;
    const int br0 = wn * 32 + lr, br1 = wn * 32 + 16 + lr;
#pragma unroll
    for (int kh = 0; kh < 2; ++kh) {
      const int ksb = kh * 4 + kg;
      auto rd = [&](const unsigned int* P, int row) {
        return *(const bf16x8*)(P + row * 32 + ((ksb ^ (row & 7)) << 2));
      };
      bf16x8 a0h = rd(Ah, ar0), a0l = rd(Al, ar0);
      bf16x8 a1h = rd(Ah, ar1), a1l = rd(Al, ar1);
      bf16x8 b0h = rd(Bh, br0), b0l = rd(Bl, br0);
      bf16x8 b1h = rd(Bh, br1), b1l = rd(Bl, br1);
      acc00 = __builtin_amdgcn_mfma_f32_16x16x32_bf16(a0h, b0h, acc00, 0, 0, 0);
      acc00 = __builtin_amdgcn_mfma_f32_16x16x32_bf16(a0h, b0l, acc00, 0, 0, 0);
      acc00 = __builtin_amdgcn_mfma_f32_16x16x32_bf16(a0l, b0h, acc00, 0, 0, 0);
      acc01 = __builtin_amdgcn_mfma_f32_16x16x32_bf16(a0h, b1h, acc01, 0, 0, 0);
      acc01 = __builtin_amdgcn_mfma_f32_16x16x32_bf16(a0h, b1l, acc01, 0, 0, 0);
      acc01 = __builtin_amdgcn_mfma_f32_16x16x32_bf16(a0l, b1h, acc01, 0, 0, 0);
      acc10 = __builtin_amdgcn_mfma_f32_16x16x32_bf16(a1h, b0h, acc10, 0, 0, 0);
      acc10 = __builtin_amdgcn_mfma_f32_16x16x32_bf16(a1h, b0l, acc10, 0, 0, 0);
      acc10 = __builtin_amdgcn_mfma_f32_16x16x32_bf16(a1l, b0h, acc10, 0, 0, 0);
      acc11 = __builtin_amdgcn_mfma_f32_16x16x32_bf16(a1h, b1h, acc11, 0, 0, 0);
      acc11 = __builtin_amdgcn_mfma_f32_16x16x32_bf16(a1h, b1l, acc11, 0, 0, 0);
      acc11 = __builtin_amdgcn_mfma_f32_16x16x32_bf16(a1l, b1h, acc11, 0, 0, 0);
    }
    __syncthreads();
  }

  const float bv0 = HB ? bias[n0 + wn * 32 + lr] : 0.f;
  const float bv1 = HB ? bias[n0 + wn * 32 + 16 + lr] : 0.f;
  auto emit = [&](f32x4 d, int rbase, int c, float bv) {
#pragma unroll
    for (int reg = 0; reg < 4; ++reg) {
      int r = rbase + kg * 4 + reg;
      float v = d[reg];
      if (HB) v += bv;
      if (ACT == 1) v = 0.5f * v * (1.f + erff(v * 0.70710678118654752f));
      else if (ACT == 2) v = fmaxf(v, 0.f);
      else if (ACT == 3) v = (v > 0.f) ? (v + log1pf(expf(-v))) : log1pf(expf(v));
      if (HA) v += addsrc[(size_t)r * ldc + c];
      C[(size_t)r * ldc + c] = v;
    }
  };
  emit(acc00, m0 + wm * 32,      n0 + wn * 32 + lr,      bv0);
  emit(acc01, m0 + wm * 32,      n0 + wn * 32 + 16 + lr, bv1);
  emit(acc10, m0 + wm * 32 + 16, n0 + wn * 32 + lr,      bv0);
  emit(acc11, m0 + wm * 32 + 16, n0 + wn * 32 + 16 + lr, bv1);
}

// ---------------- LayerNorm ---------------
__global__ __launch_bounds__(256) void ln_kernel(const float* __restrict__ in,
                                                 const float* __restrict__ g,
                                                 const float* __restrict__ b,
                                                 float* __restrict__ out) {
  int wave = threadIdx.x >> 6, lane = threadIdx.x & 63;
  int t = blockIdx.x * 4 + wave;
  const float* row = in + (size_t)t * 512;
  float v[8];
  float s = 0.f;
#pragma unroll
  for (int j = 0; j < 8; ++j) { v[j] = row[lane + j * 64]; s += v[j]; }
#pragma unroll
  for (int o = 1; o < 64; o <<= 1) s += __shfl_xor(s, o);
  float mu = s * (1.f / 512.f);
  float q = 0.f;
#pragma unroll
  for (int j = 0; j < 8; ++j) { float d = v[j] - mu; q += d * d; }
#pragma unroll
  for (int o = 1; o < 64; o <<= 1) q += __shfl_xor(q, o);
  float rstd = rsqrtf(q * (1.f / 512.f) + 1e-5f);
  float* orow = out + (size_t)t * 512;
#pragma unroll
  for (int j = 0; j < 8; ++j) {
    int c = lane + j * 64;
    orow[c] = (v[j] - mu) * rstd * g[c] + b[c];
  }
}

// ------------- depthwise causal conv + silu ---
__global__ __launch_bounds__(256) void conv_silu_kernel(const float* __restrict__ xz,
                                                        const float* __restrict__ cw,
                                                        const float* __restrict__ cb,
                                                        float* __restrict__ xi2) {
  int dir = blockIdx.z;
  int idx = blockIdx.x * 256 + threadIdx.x;
  int d = idx & 1023, t = idx >> 10;
  int b = t >> 9, tl = t & 511;
  float acc = cb[d];
#pragma unroll
  for (int k = 0; k < 4; ++k) {
    int src = (dir == 0) ? (tl - 3 + k) : (tl + 3 - k);
    if (src >= 0 && src < 512)
      acc += cw[d * 4 + k] * xz[(size_t)(b * 512 + src) * 2048 + d];
  }
  xi2[(size_t)dir * T_TOK * 1024 + idx] = acc / (1.f + expf(-acc));
}

// -------- chunked scan pass 1: per-chunk (P = prod dA, Q = local scan) ------
__global__ __launch_bounds__(256) void scan1_kernel(const float* __restrict__ xdbl2,
                                                    const float* __restrict__ dt2,
                                                    const float* __restrict__ xi2,
                                                    const float* __restrict__ alog,
                                                    float* __restrict__ Pc,
                                                    float* __restrict__ Qc) {
  const int dir = blockIdx.z;
  const int b = blockIdx.y & 3;
  const int c = blockIdx.y >> 2;
  const int s = threadIdx.x & 15;
  const int dl = threadIdx.x >> 4;
  const int d = blockIdx.x * 16 + dl;
  const float A = -expf(alog[d * 16 + s]);
  const float* dt = dt2 + (size_t)dir * T_TOK * 1024;
  const float* xi = xi2 + (size_t)dir * T_TOK * 1024;
  const float* xd = xdbl2 + (size_t)dir * T_TOK * 64;
  float h = 0.f, P = 1.f;
#pragma unroll 4
  for (int st = c * CS; st < c * CS + CS; ++st) {
    int tt = dir ? (511 - st) : st;
    int row = b * 512 + tt;
    float dtv = dt[row * 1024 + d];
    float xiv = xi[row * 1024 + d];
    float Bv = xd[row * 64 + 32 + s];
    float dA = expf(dtv * A);
    h = fmaf(dA, h, dtv * Bv * xiv);
    P *= dA;
  }
  size_t o = ((size_t)(dir * 4 + b) * NCH + c) * 16384 + d * 16 + s;
  Pc[o] = P;
  Qc[o] = h;
}

// -------- chunked scan pass 2: prefix over chunks -> H0 ---------------------
__global__ __launch_bounds__(256) void scan2_kernel(const float* __restrict__ Pc,
                                                    const float* __restrict__ Qc,
                                                    float* __restrict__ H0) {
  int idx = blockIdx.x * 256 + threadIdx.x;  // over 2*4*16384
  int g = idx >> 14, ds = idx & 16383;
  float h = 0.f;
#pragma unroll
  for (int c = 0; c < NCH; ++c) {
    size_t o = ((size_t)g * NCH + c) * 16384 + ds;
    H0[o] = h;
    h = fmaf(Pc[o], h, Qc[o]);
  }
}

// -------- chunked scan pass 3: re-scan chunk from H0, emit y ----------------
__global__ __launch_bounds__(256) void scan3_kernel(const float* __restrict__ xdbl2,
                                                    const float* __restrict__ dt2,
                                                    const float* __restrict__ xi2,
                                                    const float* __restrict__ alog,
                                                    const float* __restrict__ Dp,
                                                    const float* __restrict__ H0,
                                                    float* __restrict__ y2) {
  const int dir = blockIdx.z;
  const int b = blockIdx.y & 3;
  const int c = blockIdx.y >> 2;
  const int s = threadIdx.x & 15;
  const int dl = threadIdx.x >> 4;
  const int d = blockIdx.x * 16 + dl;
  const float A = -expf(alog[d * 16 + s]);
  const float Dv = Dp[d];
  const float* dt = dt2 + (size_t)dir * T_TOK * 1024;
  const float* xi = xi2 + (size_t)dir * T_TOK * 1024;
  const float* xd = xdbl2 + (size_t)dir * T_TOK * 64;
  float* y = y2 + (size_t)dir * T_TOK * 1024;
  float h = H0[((size_t)(dir * 4 + b) * NCH + c) * 16384 + d * 16 + s];
#pragma unroll 4
  for (int st = c * CS; st < c * CS + CS; ++st) {
    int tt = dir ? (511 - st) : st;
    int row = b * 512 + tt;
    float dtv = dt[row * 1024 + d];
    float xiv = xi[row * 1024 + d];
    float Bv = xd[row * 64 + 32 + s];
    float Cv = xd[row * 64 + 48 + s];
    float dA = expf(dtv * A);
    h = fmaf(dA, h, dtv * Bv * xiv);
    float p = h * Cv;
    p += __shfl_xor(p, 1);
    p += __shfl_xor(p, 2);
    p += __shfl_xor(p, 4);
    p += __shfl_xor(p, 8);
    if (s == 0) y[row * 1024 + d] = p + Dv * xiv;
  }
}

// ---------------- g = silu(z) * (y_fwd + y_bwd) ------------------------------
__global__ __launch_bounds__(256) void gmul_kernel(const float* __restrict__ xz,
                                                   const float* __restrict__ y2,
                                                   float* __restrict__ g) {
  int idx = blockIdx.x * 256 + threadIdx.x;
  int d = idx & 1023, t = idx >> 10;
  float z = xz[(size_t)t * 2048 + 1024 + d];
  float y = y2[idx] + y2[(size_t)T_TOK * 1024 + idx];
  g[idx] = z / (1.f + expf(-z)) * y;
}

// ---------------- MoE gate ------------------
__global__ __launch_bounds__(256) void gate_kernel(const float* __restrict__ h,
                                                   const float* __restrict__ gw,
                                                   const float* __restrict__ gb,
                                                   float* __restrict__ topv) {
  int wave = threadIdx.x >> 6, lane = threadIdx.x & 63;
  int t = blockIdx.x * 4 + wave;
  float acc[8] = {0.f, 0.f, 0.f, 0.f, 0.f, 0.f, 0.f, 0.f};
  for (int k = lane; k < 512; k += 64) {
    float hv = h[(size_t)t * 512 + k];
#pragma unroll
    for (int e = 0; e < 8; ++e) acc[e] = fmaf(hv, gw[e * 512 + k], acc[e]);
  }
#pragma unroll
  for (int e = 0; e < 8; ++e)
#pragma unroll
    for (int o = 1; o < 64; o <<= 1) acc[e] += __shfl_xor(acc[e], o);
  if (lane == 0) {
    float zmax = -1e30f;
#pragma unroll
    for (int e = 0; e < 8; ++e) {
      acc[e] += gb[e];
      zmax = fmaxf(zmax, acc[e]);
    }
    float ssum = 0.f;
#pragma unroll
    for (int e = 0; e < 8; ++e) ssum += expf(acc[e] - zmax);
    topv[t] = 1.f / ssum;
  }
}

// ---------------- h = e3 * topv[t] ------------------------------------------
__global__ __launch_bounds__(256) void scale_kernel(const float* __restrict__ e3,
                                                    const float* __restrict__ topv,
                                                    float* __restrict__ h) {
  int idx = blockIdx.x * 256 + threadIdx.x;
  h[idx] = e3[idx] * topv[idx >> 9];
}

// ---------------- final head ---------------
__global__ __launch_bounds__(256) void final_kernel(const float* __restrict__ h,
                                                    const float* __restrict__ fcw,
                                                    const float* __restrict__ fcb,
                                                    float* __restrict__ out) {
  int wave = threadIdx.x >> 6, lane = threadIdx.x & 63;
  int t = blockIdx.x * 4 + wave;
  float acc[10] = {0.f, 0.f, 0.f, 0.f, 0.f, 0.f, 0.f, 0.f, 0.f, 0.f};
  for (int k = lane; k < 512; k += 64) {
    float hv = h[(size_t)t * 512 + k];
#pragma unroll
    for (int c = 0; c < 10; ++c) acc[c] = fmaf(hv, fcw[c * 512 + k], acc[c]);
  }
#pragma unroll
  for (int c = 0; c < 10; ++c)
#pragma unroll
    for (int o = 1; o < 64; o <<= 1) acc[c] += __shfl_xor(acc[c], o);
  if (lane == 0) {
#pragma unroll
    for (int c = 0; c < 10; ++c)
      out[(size_t)t * 10 + c] = acc[c] + fcb[c];
  }
}

extern "C" void kernel_launch(void* const* d_in, const int* in_sizes, int n_in,
                              void* d_out, int out_size, void* d_ws, size_t ws_size,
                              hipStream_t stream) {
  (void)in_sizes; (void)n_in; (void)out_size; (void)ws_size;
  const float* x_in  = (const float*)d_in[0];
  const float* inp_w = (const float*)d_in[1];
  const float* inp_b = (const float*)d_in[2];
  const float* n1g   = (const float*)d_in[3];
  const float* n1b   = (const float*)d_in[4];
  const float* inw   = (const float*)d_in[5];
  const float* cw    = (const float*)d_in[6];
  const float* cb    = (const float*)d_in[7];
  const float* xpw   = (const float*)d_in[8];
  const float* dtw   = (const float*)d_in[9];
  const float* dtb   = (const float*)d_in[10];
  const float* alog  = (const float*)d_in[11];
  const float* Dp    = (const float*)d_in[12];
  const float* ow    = (const float*)d_in[13];
  const float* n2g   = (const float*)d_in[14];
  const float* n2b   = (const float*)d_in[15];
  const float* fw1   = (const float*)d_in[16];
  const float* fb1   = (const float*)d_in[17];
  const float* fw2   = (const float*)d_in[18];
  const float* fb2   = (const float*)d_in[19];
  const float* gw    = (const float*)d_in[20];
  const float* gb    = (const float*)d_in[21];
  const float* ew1   = (const float*)d_in[22];
  const float* eb1   = (const float*)d_in[23];
  const float* ew2   = (const float*)d_in[24];
  const float* eb2   = (const float*)d_in[25];
  const float* ew3   = (const float*)d_in[26];
  const float* eb3   = (const float*)d_in[27];
  const float* fcw   = (const float*)d_in[28];
  const float* fcb   = (const float*)d_in[29];

  float* p = (float*)d_ws;
  size_t off = 0;
  auto alloc = [&](size_t n) { float* r = p + off; off += n; return r; };
  float* h     = alloc(1048576);
  float* res   = alloc(1048576);
  float* hn    = alloc(1048576);
  float* xz    = alloc(4194304);
  float* xi2   = alloc(2u * 2097152);
  float* xdbl2 = alloc(2u * 131072);
  float* dt2   = alloc(2u * 2097152);
  float* y2    = alloc(2u * 2097152);
  float* g     = alloc(2097152);
  float* fb    = alloc(1048576);
  float* mbuf  = alloc(1048576);
  float* e1    = alloc(524288);
  float* e2    = alloc(524288);
  float* e3    = alloc(1048576);
  float* topv  = alloc(2048);
  float* Pc    = alloc(2097152);  // [2*4][16 chunks][16384]
  float* Qc    = alloc(2097152);
  float* H0    = alloc(2097152);

  unsigned short* q = (unsigned short*)(p + off);
  size_t qoff = 0;
  auto ualloc = [&](size_t n) { unsigned short* r = q + qoff; qoff += n; return r; };
  unsigned short *inpwH = ualloc(65536),  *inpwL = ualloc(65536);
  unsigned short *inwH  = ualloc(2097152), *inwL  = ualloc(2097152);
  unsigned short *xpwH  = ualloc(131072),  *xpwL  = ualloc(131072);
  unsigned short *dtwH  = ualloc(65536),   *dtwL  = ualloc(65536);
  unsigned short *owH   = ualloc(1048576), *owL   = ualloc(1048576);
  unsigned short *fw1H  = ualloc(2097152), *fw1L  = ualloc(2097152);
  unsigned short *fw2H  = ualloc(2097152), *fw2L  = ualloc(2097152);
  unsigned short *ew1H  = ualloc(131072),  *ew1L  = ualloc(131072);
  unsigned short *ew2H  = ualloc(65536),   *ew2L  = ualloc(65536);
  unsigned short *ew3H  = ualloc(131072),  *ew3L  = ualloc(131072);

  auto split = [&](const float* src, unsigned short* hi, unsigned short* lo, int n) {
    split_kernel<<<(n / 4 + 255) / 256, 256, 0, stream>>>(src, hi, lo, n);
  };
  split(inp_w, inpwH, inpwL, 65536);
  split(inw,   inwH,  inwL,  2097152);
  split(xpw,   xpwH,  xpwL,  131072);
  split(dtw,   dtwH,  dtwL,  65536);
  split(ow,    owH,   owL,   1048576);
  split(fw1,   fw1H,  fw1L,  2097152);
  split(fw2,   fw2H,  fw2L,  2097152);
  split(ew1,   ew1H,  ew1L,  131072);
  split(ew2,   ew2H,  ew2L,  65536);
  split(ew3,   ew3H,  ew3L,  131072);

  mfmm_kernel<0, true, false><<<dim3(8, 32), 256, 0, stream>>>(
      x_in, 128, inpwH, inpwL, 128, inp_b, nullptr, h, 512, 128);

  for (int i = 0; i < 2; ++i) {
    const size_t wo = (size_t)i;
    hipMemcpyAsync(res, h, (size_t)1048576 * 4, hipMemcpyDeviceToDevice, stream);
    ln_kernel<<<512, 256, 0, stream>>>(h, n1g + i * 512, n1b + i * 512, hn);
    mfmm_kernel<0, false, false><<<dim3(32, 32), 256, 0, stream>>>(
        hn, 512, inwH + wo * 1048576, inwL + wo * 1048576, 512, nullptr, nullptr, xz, 2048, 512);
    conv_silu_kernel<<<dim3(8192, 1, 2), 256, 0, stream>>>(xz, cw + i * 4096, cb + i * 1024, xi2);
    mfmm_kernel<0, false, false><<<dim3(1, 64), 256, 0, stream>>>(
        xi2, 1024, xpwH + wo * 65536, xpwL + wo * 65536, 1024, nullptr, nullptr, xdbl2, 64, 1024);
    mfmm_kernel<3, true, false><<<dim3(16, 64), 256, 0, stream>>>(
        xdbl2, 64, dtwH + wo * 32768, dtwL + wo * 32768, 32, dtb + i * 1024, nullptr, dt2, 1024, 32);
    // chunked parallel scan
    scan1_kernel<<<dim3(64, 64, 2), 256, 0, stream>>>(
        xdbl2, dt2, xi2, alog + i * 16384, Pc, Qc);
    scan2_kernel<<<512, 256, 0, stream>>>(Pc, Qc, H0);
    scan3_kernel<<<dim3(64, 64, 2), 256, 0, stream>>>(
        xdbl2, dt2, xi2, alog + i * 16384, Dp + i * 1024, H0, y2);
    gmul_kernel<<<8192, 256, 0, stream>>>(xz, y2, g);
    mfmm_kernel<0, false, false><<<dim3(8, 32), 256, 0, stream>>>(
        g, 1024, owH + wo * 524288, owL + wo * 524288, 1024, nullptr, nullptr, fb, 512, 1024);
    ln_kernel<<<512, 256, 0, stream>>>(fb, n2g + i * 512, n2b + i * 512, mbuf);
    mfmm_kernel<1, true, false><<<dim3(32, 32), 256, 0, stream>>>(
        mbuf, 512, fw1H + wo * 1048576, fw1L + wo * 1048576, 512, fb1 + i * 2048, nullptr, xz, 2048, 512);
    mfmm_kernel<0, true, true><<<dim3(8, 32), 256, 0, stream>>>(
        xz, 2048, fw2H + wo * 1048576, fw2L + wo * 1048576, 2048, fb2 + i * 512, res, h, 512, 2048);
    gate_kernel<<<512, 256, 0, stream>>>(h, gw, gb, topv);
    mfmm_kernel<2, true, false><<<dim3(4, 32), 256, 0, stream>>>(
        h, 512, ew1H, ew1L, 512, eb1, nullptr, e1, 256, 512);
    mfmm_kernel<2, true, false><<<dim3(4, 32), 256, 0, stream>>>(
        e1, 256, ew2H, ew2L, 256, eb2, nullptr, e2, 256, 256);
    mfmm_kernel<2, true, false><<<dim3(8, 32), 256, 0, stream>>>(
        e2, 256, ew3H, ew3L, 256, eb3, nullptr, e3, 512, 256);
    scale_kernel<<<4096, 256, 0, stream>>>(e3, topv, h);
  }
  final_kernel<<<512, 256, 0, stream>>>(h, fcw, fcb, (float*)d_out);
}